// Round 2
// baseline (1755.106 us; speedup 1.0000x reference)
//
#include <hip/hip_runtime.h>
#include <hip/hip_bf16.h>

// GRU (TF GRUCell), B=2048, T=12, D=512, H=1024, fp32 in/out.
// R2: x-contribution hoisted into one big parallel GEMM (Px, bf16);
// sequential steps only do h-GEMMs (K=1024) with 4x4 wave tiles,
// depth-4 register pipeline, XCD-friendly N-major grid. LDS-free.

#define T_SEQ 12
#define BATCH 2048
#define IND 512
#define HID 1024
#define NGATE (2 * HID)         // 2048
#define NPRE (NGATE + HID)      // 3072 combined x-proj width
#define KS_X (IND / 32)         // 16
#define KS_H (HID / 32)         // 32

typedef __bf16 bf16x8 __attribute__((ext_vector_type(8)));
typedef __bf16 bf16x4 __attribute__((ext_vector_type(4)));
typedef float floatx4 __attribute__((ext_vector_type(4)));

__device__ __forceinline__ float fast_sigmoid(float v) {
  v = fminf(30.f, fmaxf(-30.f, v));
  return 1.f / (1.f + __expf(-v));
}
__device__ __forceinline__ float fast_tanh(float v) {
  v = fminf(15.f, fmaxf(-15.f, v));
  float e = __expf(2.f * v);
  return (e - 1.f) / (e + 1.f);
}

// Pack rows [row0, row0+ksteps*32) of W [*, ld] fp32 into MFMA-B fragment
// order bf16: out[((n_tile*ksteps + k_tile)*64 + lane)*8 + j]
//   = W[row0 + k_tile*32 + (lane>>4)*8 + j][n_tile*16 + (lane&15)]
__global__ void pack_w(const float* __restrict__ W, int ld, int row0, int ksteps,
                       __bf16* __restrict__ out) {
  int gid = blockIdx.x * blockDim.x + threadIdx.x;
  int wid = gid >> 6;
  int lane = gid & 63;
  int n_tile = wid / ksteps;
  int k_tile = wid - n_tile * ksteps;
  int col = n_tile * 16 + (lane & 15);
  int k0 = row0 + k_tile * 32 + (lane >> 4) * 8;
  bf16x8 v;
#pragma unroll
  for (int j = 0; j < 8; ++j) v[j] = (__bf16)W[(size_t)(k0 + j) * ld + col];
  *reinterpret_cast<bf16x8*>(out + (size_t)wid * 512 + lane * 8) = v;
}

__global__ void cvt_bf16(const float4* __restrict__ in, __bf16* __restrict__ out, int n4) {
  int i = blockIdx.x * blockDim.x + threadIdx.x;
  if (i >= n4) return;
  float4 v = in[i];
  bf16x4 o;
  o[0] = (__bf16)v.x; o[1] = (__bf16)v.y; o[2] = (__bf16)v.z; o[3] = (__bf16)v.w;
  *reinterpret_cast<bf16x4*>(out + (size_t)i * 4) = o;
}

__global__ void init_h(const float4* __restrict__ coded, float4* __restrict__ h32,
                       __bf16* __restrict__ hb, int n4) {
  int i = blockIdx.x * blockDim.x + threadIdx.x;
  if (i >= n4) return;
  float4 v = coded[i];
  h32[i] = v;
  bf16x4 o;
  o[0] = (__bf16)v.x; o[1] = (__bf16)v.y; o[2] = (__bf16)v.z; o[3] = (__bf16)v.w;
  *reinterpret_cast<bf16x4*>(hb + (size_t)i * 4) = o;
}

// ---- shared 4x4 wave-tile MFMA core (depth-4 register pipeline) ----
// A-fragment: lane holds A[m0+mf*16+(lane&15)][ks*32 + (lane>>4)*8 .. +7]
// B-fragment: packed layout above. acc C/D: col=n0+nf*16+(lane&15),
// row=m0+mf*16+(lane>>4)*4+i.

// Precompute: Px = Xflat[24576,512] @ Wx[512,3072]; cols 0..2047 -> Pg(+bg),
// 2048..3071 -> Pc(+bc). bf16 outputs.
__global__ __launch_bounds__(256) void pre_gemm(
    const __bf16* __restrict__ Xb, const __bf16* __restrict__ Wp,
    const float* __restrict__ bg, const float* __restrict__ bc,
    __bf16* __restrict__ Pg, __bf16* __restrict__ Pc) {
  const int lane = threadIdx.x & 63;
  const int wave = threadIdx.x >> 6;
  const int quad = lane >> 4;
  const int l16 = lane & 15;
  const int m0 = blockIdx.x * 128 + (wave >> 1) * 64;
  const int n0 = blockIdx.y * 128 + (wave & 1) * 64;

  const __bf16* ap[4];
  const __bf16* bp[4];
#pragma unroll
  for (int mf = 0; mf < 4; ++mf)
    ap[mf] = Xb + (size_t)(m0 + mf * 16 + l16) * IND + quad * 8;
#pragma unroll
  for (int nf = 0; nf < 4; ++nf)
    bp[nf] = Wp + ((size_t)((n0 >> 4) + nf) * KS_X) * 512 + (size_t)lane * 8;

  floatx4 acc[4][4] = {};
  bf16x8 aq[4][4], bq[4][4];
#pragma unroll
  for (int s = 0; s < 3; ++s) {
#pragma unroll
    for (int mf = 0; mf < 4; ++mf) aq[s][mf] = *reinterpret_cast<const bf16x8*>(ap[mf] + s * 32);
#pragma unroll
    for (int nf = 0; nf < 4; ++nf) bq[s][nf] = *reinterpret_cast<const bf16x8*>(bp[nf] + (size_t)s * 512);
  }
#pragma unroll
  for (int ks = 0; ks < KS_X; ++ks) {
    const int cur = ks & 3;
    const int nxt = (ks + 3) & 3;
    if (ks + 3 < KS_X) {
#pragma unroll
      for (int mf = 0; mf < 4; ++mf) aq[nxt][mf] = *reinterpret_cast<const bf16x8*>(ap[mf] + (ks + 3) * 32);
#pragma unroll
      for (int nf = 0; nf < 4; ++nf) bq[nxt][nf] = *reinterpret_cast<const bf16x8*>(bp[nf] + (size_t)(ks + 3) * 512);
    }
#pragma unroll
    for (int mf = 0; mf < 4; ++mf)
#pragma unroll
      for (int nf = 0; nf < 4; ++nf)
        acc[mf][nf] = __builtin_amdgcn_mfma_f32_16x16x32_bf16(aq[cur][mf], bq[cur][nf], acc[mf][nf], 0, 0, 0);
  }

#pragma unroll
  for (int mf = 0; mf < 4; ++mf) {
#pragma unroll
    for (int nf = 0; nf < 4; ++nf) {
      int col = n0 + nf * 16 + l16;
      float bv = (col < NGATE) ? bg[col] : bc[col - NGATE];
#pragma unroll
      for (int i = 0; i < 4; ++i) {
        int row = m0 + mf * 16 + quad * 4 + i;
        float v = acc[mf][nf][i] + bv;
        if (col < NGATE)
          Pg[(size_t)row * NGATE + col] = (__bf16)v;
        else
          Pc[(size_t)row * HID + (col - NGATE)] = (__bf16)v;
      }
    }
  }
}

// Sequential step GEMMs. Grid: x = N-tile (XCD locality), y = M-tile.
// PHASE 0: gates = sigmoid(h@Wgh + Pg); writes rhb, u32.
// PHASE 1: c = tanh(rh@Wch + Pc); h = u*h+(1-u)*c; writes h32,hb,out.
template <int PHASE>
__global__ __launch_bounds__(256) void gru_step4(
    const __bf16* __restrict__ Arec,  // ph0: hb; ph1: rhb  [B,H]
    const __bf16* __restrict__ Wp,    // packed h-weights (KS_H)
    const __bf16* __restrict__ Px,    // ph0: Pg [B*T,2048]; ph1: Pc [B*T,1024]
    float* __restrict__ h32,
    __bf16* __restrict__ hb,
    float* __restrict__ u32,
    __bf16* __restrict__ rhb,
    float* __restrict__ out,
    int t) {
  const int lane = threadIdx.x & 63;
  const int wave = threadIdx.x >> 6;
  const int quad = lane >> 4;
  const int l16 = lane & 15;
  const int n0 = blockIdx.x * 128 + (wave & 1) * 64;
  const int m0 = blockIdx.y * 128 + (wave >> 1) * 64;

  const __bf16* ap[4];
  const __bf16* bp[4];
#pragma unroll
  for (int mf = 0; mf < 4; ++mf)
    ap[mf] = Arec + (size_t)(m0 + mf * 16 + l16) * HID + quad * 8;
#pragma unroll
  for (int nf = 0; nf < 4; ++nf)
    bp[nf] = Wp + ((size_t)((n0 >> 4) + nf) * KS_H) * 512 + (size_t)lane * 8;

  floatx4 acc[4][4] = {};
  bf16x8 aq[4][4], bq[4][4];
#pragma unroll
  for (int s = 0; s < 3; ++s) {
#pragma unroll
    for (int mf = 0; mf < 4; ++mf) aq[s][mf] = *reinterpret_cast<const bf16x8*>(ap[mf] + s * 32);
#pragma unroll
    for (int nf = 0; nf < 4; ++nf) bq[s][nf] = *reinterpret_cast<const bf16x8*>(bp[nf] + (size_t)s * 512);
  }
#pragma unroll
  for (int ks = 0; ks < KS_H; ++ks) {
    const int cur = ks & 3;
    const int nxt = (ks + 3) & 3;
    if (ks + 3 < KS_H) {
#pragma unroll
      for (int mf = 0; mf < 4; ++mf) aq[nxt][mf] = *reinterpret_cast<const bf16x8*>(ap[mf] + (ks + 3) * 32);
#pragma unroll
      for (int nf = 0; nf < 4; ++nf) bq[nxt][nf] = *reinterpret_cast<const bf16x8*>(bp[nf] + (size_t)(ks + 3) * 512);
    }
#pragma unroll
    for (int mf = 0; mf < 4; ++mf)
#pragma unroll
      for (int nf = 0; nf < 4; ++nf)
        acc[mf][nf] = __builtin_amdgcn_mfma_f32_16x16x32_bf16(aq[cur][mf], bq[cur][nf], acc[mf][nf], 0, 0, 0);
  }

#pragma unroll
  for (int mf = 0; mf < 4; ++mf) {
#pragma unroll
    for (int nf = 0; nf < 4; ++nf) {
      int col = n0 + nf * 16 + l16;
#pragma unroll
      for (int i = 0; i < 4; ++i) {
        int row = m0 + mf * 16 + quad * 4 + i;
        if (PHASE == 0) {
          float v = acc[mf][nf][i] + (float)Px[((size_t)row * T_SEQ + t) * NGATE + col];
          float s = fast_sigmoid(v);
          if (col < HID) {
            size_t idx = (size_t)row * HID + col;
            rhb[idx] = (__bf16)(s * h32[idx]);
          } else {
            u32[(size_t)row * HID + (col - HID)] = s;
          }
        } else {
          float v = acc[mf][nf][i] + (float)Px[((size_t)row * T_SEQ + t) * HID + col];
          float c = fast_tanh(v);
          size_t idx = (size_t)row * HID + col;
          float u = u32[idx];
          float hnew = u * h32[idx] + (1.f - u) * c;
          h32[idx] = hnew;
          hb[idx] = (__bf16)hnew;
          out[((size_t)row * T_SEQ + t) * HID + col] = hnew;
        }
      }
    }
  }
}

extern "C" void kernel_launch(void* const* d_in, const int* in_sizes, int n_in,
                              void* d_out, int out_size, void* d_ws, size_t ws_size,
                              hipStream_t stream) {
  const float* x     = (const float*)d_in[0];
  const float* coded = (const float*)d_in[1];
  const float* Wg_f  = (const float*)d_in[2];
  const float* bg    = (const float*)d_in[3];
  const float* Wc_f  = (const float*)d_in[4];
  const float* bc    = (const float*)d_in[5];
  float* out = (float*)d_out;

  uintptr_t base = ((uintptr_t)d_ws + 255) & ~(uintptr_t)255;
  auto take = [&](size_t bytes) {
    void* p = (void*)base;
    base = (base + bytes + 255) & ~(uintptr_t)255;
    return p;
  };
  // packed weights
  __bf16* Bx  = (__bf16*)take((size_t)(NPRE / 16) * KS_X * 512 * 2);   // 3.1 MB
  __bf16* Bhg = (__bf16*)take((size_t)(NGATE / 16) * KS_H * 512 * 2);  // 4.2 MB
  __bf16* Bhc = (__bf16*)take((size_t)(HID / 16) * KS_H * 512 * 2);    // 2.1 MB
  // activations / state
  __bf16* Xb  = (__bf16*)take((size_t)BATCH * T_SEQ * IND * 2);        // 25.2 MB
  __bf16* Pg  = (__bf16*)take((size_t)BATCH * T_SEQ * NGATE * 2);      // 100.7 MB
  __bf16* Pc  = (__bf16*)take((size_t)BATCH * T_SEQ * HID * 2);        // 50.3 MB
  float*  h32 = (float*) take((size_t)BATCH * HID * 4);                // 8.4 MB
  __bf16* hb  = (__bf16*)take((size_t)BATCH * HID * 2);                // 4.2 MB
  float*  u32 = (float*) take((size_t)BATCH * HID * 4);                // 8.4 MB
  __bf16* rhb = (__bf16*)take((size_t)BATCH * HID * 2);                // 4.2 MB

  // pack weights: x-parts (combined region) then h-parts
  pack_w<<<(NGATE / 16) * KS_X * 64 / 256, 256, 0, stream>>>(Wg_f, NGATE, 0, KS_X, Bx);
  pack_w<<<(HID / 16) * KS_X * 64 / 256, 256, 0, stream>>>(
      Wc_f, HID, 0, KS_X, Bx + (size_t)(NGATE / 16) * KS_X * 512);
  pack_w<<<(NGATE / 16) * KS_H * 64 / 256, 256, 0, stream>>>(Wg_f, NGATE, IND, KS_H, Bhg);
  pack_w<<<(HID / 16) * KS_H * 64 / 256, 256, 0, stream>>>(Wc_f, HID, IND, KS_H, Bhc);
  cvt_bf16<<<(BATCH * T_SEQ * IND / 4 + 255) / 256, 256, 0, stream>>>(
      (const float4*)x, Xb, BATCH * T_SEQ * IND / 4);
  init_h<<<(BATCH * HID / 4 + 255) / 256, 256, 0, stream>>>(
      (const float4*)coded, (float4*)h32, hb, BATCH * HID / 4);

  // big parallel x-projection for all timesteps
  pre_gemm<<<dim3(BATCH * T_SEQ / 128, NPRE / 128), 256, 0, stream>>>(Xb, Bx, bg, bc, Pg, Pc);

  // recurrence
  for (int t = 0; t < T_SEQ; ++t) {
    gru_step4<0><<<dim3(NGATE / 128, BATCH / 128), 256, 0, stream>>>(
        hb, Bhg, Pg, h32, hb, u32, rhb, out, t);
    gru_step4<1><<<dim3(HID / 128, BATCH / 128), 256, 0, stream>>>(
        rhb, Bhc, Pc, h32, hb, u32, rhb, out, t);
  }
}

// Round 3
// 992.654 us; speedup vs baseline: 1.7681x; 1.7681x over previous
//
#include <hip/hip_runtime.h>
#include <hip/hip_bf16.h>

// GRU (TF GRUCell), B=2048, T=12, D=512, H=1024, fp32 in/out.
// R3: all GEMMs use LDS-staged K-loop (m97-style, register-prefetch pipeline,
// BK=64), wave tile 32x64 (2x4 frags). Px (x-projection, all t) stored in
// MFMA fragment order so step epilogues do vector loads. XCD n-major grids.

#define T_SEQ 12
#define BATCH 2048
#define IND 512
#define HID 1024
#define NGATE (2 * HID)  // 2048
#define NPRE (NGATE + HID)

typedef __bf16 bf16x8 __attribute__((ext_vector_type(8)));
typedef __bf16 bf16x4 __attribute__((ext_vector_type(4)));
typedef float floatx4 __attribute__((ext_vector_type(4)));

__device__ __forceinline__ float fast_sigmoid(float v) {
  v = fminf(30.f, fmaxf(-30.f, v));
  return 1.f / (1.f + __expf(-v));
}
__device__ __forceinline__ float fast_tanh(float v) {
  v = fminf(15.f, fmaxf(-15.f, v));
  float e = __expf(2.f * v);
  return (e - 1.f) / (e + 1.f);
}

// Pack rows [row0, row0+ksteps*32) of W [*, ld] fp32 -> bf16 MFMA-B frag order:
// out[((n16*ksteps + ktile)*64 + lane)*8 + j]
//   = W[row0 + ktile*32 + (lane>>4)*8 + j][n16*16 + (lane&15)]
__global__ void pack_w(const float* __restrict__ W, int ld, int row0, int ksteps,
                       __bf16* __restrict__ out) {
  int gid = blockIdx.x * blockDim.x + threadIdx.x;
  int wid = gid >> 6;
  int lane = gid & 63;
  int n16 = wid / ksteps;
  int ktile = wid - n16 * ksteps;
  int col = n16 * 16 + (lane & 15);
  int k0 = row0 + ktile * 32 + (lane >> 4) * 8;
  bf16x8 v;
#pragma unroll
  for (int j = 0; j < 8; ++j) v[j] = (__bf16)W[(size_t)(k0 + j) * ld + col];
  *reinterpret_cast<bf16x8*>(out + (size_t)wid * 512 + lane * 8) = v;
}

__global__ void cvt_bf16(const float4* __restrict__ in, __bf16* __restrict__ out, int n4) {
  int i = blockIdx.x * blockDim.x + threadIdx.x;
  if (i >= n4) return;
  float4 v = in[i];
  bf16x4 o;
  o[0] = (__bf16)v.x; o[1] = (__bf16)v.y; o[2] = (__bf16)v.z; o[3] = (__bf16)v.w;
  *reinterpret_cast<bf16x4*>(out + (size_t)i * 4) = o;
}

__global__ void init_h(const float4* __restrict__ coded, float4* __restrict__ h32,
                       __bf16* __restrict__ hb, int n4) {
  int i = blockIdx.x * blockDim.x + threadIdx.x;
  if (i >= n4) return;
  float4 v = coded[i];
  h32[i] = v;
  bf16x4 o;
  o[0] = (__bf16)v.x; o[1] = (__bf16)v.y; o[2] = (__bf16)v.z; o[3] = (__bf16)v.w;
  *reinterpret_cast<bf16x4*>(hb + (size_t)i * 4) = o;
}

// Unified LDS-staged GEMM. Block tile 64(M) x BN, BN = NWN*64. Wave tile 32x64.
// MODE 0: pre  (A=Xb slice for t=blockIdx.z, K=512)  -> Px frag-order bf16
// MODE 1: gate (A=hb,  K=1024) -> rhb / u32
// MODE 2: cand (A=rhb, K=1024) -> h32/hb/out
// Px frag layout per 32x64 tile: elem(mf,nf,lane,i) at ((mf*4+nf)*64+lane)*4+i,
// tile index (t, row>>5, col>>6).
template <int NWN, int KITER, int MODE>
__global__ __launch_bounds__(NWN * 128) void gk(
    const __bf16* __restrict__ A, int ldA,
    const __bf16* __restrict__ Bp,
    const float* __restrict__ b0, const float* __restrict__ b1,
    __bf16* __restrict__ Pg, __bf16* __restrict__ Pc,
    float* __restrict__ h32, __bf16* __restrict__ hb,
    float* __restrict__ u32, __bf16* __restrict__ rhb,
    float* __restrict__ out, int t) {
  constexpr int BN = NWN * 64;
  constexpr int THREADS = NWN * 128;
  constexpr int KSTOT = KITER * 2;     // ksteps of 32 (packed-B addressing)
  constexpr int CA = 512 / THREADS;    // A 16B-chunks per thread
  constexpr int CB = 4;                // B 16B-chunks per thread

  __shared__ __bf16 Alds[64 * 72];     // 64 rows x 64 k, padded to 72 (conflict-free b128)
  __shared__ __bf16 Blds[NWN * 4096];  // chunk order [ks2][n16][lane][8]

  const int tid = threadIdx.x;
  const int lane = tid & 63;
  const int w = tid >> 6;
  const int wm = (NWN == 2) ? (w >> 1) : w;
  const int wn = (NWN == 2) ? (w & 1) : 0;
  const int quad = lane >> 4;
  const int l16 = lane & 15;
  const int m0 = blockIdx.y * 64;
  const int n0 = blockIdx.x * BN;
  const int n16b = n0 >> 4;
  const int tz = (MODE == 0) ? blockIdx.z : t;
  const __bf16* Ab = (MODE == 0) ? (A + tz * IND) : A;

  // staging address precompute
  const __bf16* gA[CA];
  int ldsA[CA];
#pragma unroll
  for (int i = 0; i < CA; ++i) {
    int c = tid + i * THREADS;                 // c in [0,512): row=c>>3, k8=c&7
    gA[i] = Ab + (size_t)(m0 + (c >> 3)) * ldA + (c & 7) * 8;
    ldsA[i] = (c >> 3) * 72 + (c & 7) * 8;
  }
  const __bf16* gB[CB];
  int ldsB[CB];
#pragma unroll
  for (int i = 0; i < CB; ++i) {
    int c = tid + i * THREADS;                 // [0, NWN*512)
    int ks2c = c / (NWN * 256);
    int rem = c % (NWN * 256);
    gB[i] = Bp + (((size_t)(n16b + rem / 64) * KSTOT + ks2c) * 64 + (rem % 64)) * 8;
    ldsB[i] = c * 8;
  }

  bf16x8 ra[CA], rb[CB];
#pragma unroll
  for (int i = 0; i < CA; ++i) ra[i] = *(const bf16x8*)(gA[i]);
#pragma unroll
  for (int i = 0; i < CB; ++i) rb[i] = *(const bf16x8*)(gB[i]);

  floatx4 acc[2][4] = {};

  for (int it = 0; it < KITER; ++it) {
    __syncthreads();
#pragma unroll
    for (int i = 0; i < CA; ++i) *(bf16x8*)&Alds[ldsA[i]] = ra[i];
#pragma unroll
    for (int i = 0; i < CB; ++i) *(bf16x8*)&Blds[ldsB[i]] = rb[i];
    __syncthreads();
    if (it + 1 < KITER) {  // prefetch next iter while computing this one
#pragma unroll
      for (int i = 0; i < CA; ++i) ra[i] = *(const bf16x8*)(gA[i] + (size_t)(it + 1) * 64);
#pragma unroll
      for (int i = 0; i < CB; ++i) rb[i] = *(const bf16x8*)(gB[i] + (size_t)(it + 1) * 1024);
    }
#pragma unroll
    for (int ks2 = 0; ks2 < 2; ++ks2) {
      bf16x8 af[2], bfr[4];
#pragma unroll
      for (int mf = 0; mf < 2; ++mf)
        af[mf] = *(const bf16x8*)&Alds[(wm * 32 + mf * 16 + l16) * 72 + ks2 * 32 + quad * 8];
#pragma unroll
      for (int nf = 0; nf < 4; ++nf)
        bfr[nf] = *(const bf16x8*)&Blds[(ks2 * NWN * 256 + (wn * 4 + nf) * 64 + lane) * 8];
#pragma unroll
      for (int mf = 0; mf < 2; ++mf)
#pragma unroll
        for (int nf = 0; nf < 4; ++nf)
          acc[mf][nf] = __builtin_amdgcn_mfma_f32_16x16x32_bf16(af[mf], bfr[nf], acc[mf][nf], 0, 0, 0);
    }
  }

  const int m32 = (m0 >> 5) + wm;
  const int n64g = (n0 >> 6) + wn;

  if (MODE == 0) {
    const bool isg = (n64g < 32);
    __bf16* P = isg ? Pg : Pc;
    const float* bias = isg ? b0 : b1;
    size_t tb = isg ? (((size_t)tz * 64 + m32) * 32 + n64g) * 2048
                    : (((size_t)tz * 64 + m32) * 16 + (n64g - 32)) * 2048;
    int colb = (isg ? n64g * 64 : (n64g - 32) * 64) + l16;
#pragma unroll
    for (int mf = 0; mf < 2; ++mf)
#pragma unroll
      for (int nf = 0; nf < 4; ++nf) {
        float bv = bias[colb + nf * 16];
        bf16x4 st;
#pragma unroll
        for (int i = 0; i < 4; ++i) st[i] = (__bf16)(acc[mf][nf][i] + bv);
        *(bf16x4*)&P[tb + (size_t)((mf * 4 + nf) * 64 + lane) * 4] = st;
      }
  } else if (MODE == 1) {
    size_t tb = (((size_t)t * 64 + m32) * 32 + n64g) * 2048;
    const bool isr = (n64g < 16);
#pragma unroll
    for (int mf = 0; mf < 2; ++mf)
#pragma unroll
      for (int nf = 0; nf < 4; ++nf) {
        bf16x4 px = *(const bf16x4*)&Pg[tb + (size_t)((mf * 4 + nf) * 64 + lane) * 4];
        int col = n0 + wn * 64 + nf * 16 + l16;
        int row = m0 + wm * 32 + mf * 16 + quad * 4;
#pragma unroll
        for (int i = 0; i < 4; ++i) {
          float s = fast_sigmoid(acc[mf][nf][i] + (float)px[i]);
          if (isr) {
            size_t idx = (size_t)(row + i) * HID + col;
            rhb[idx] = (__bf16)(s * h32[idx]);
          } else {
            u32[(size_t)(row + i) * HID + (col - HID)] = s;
          }
        }
      }
  } else {
    size_t tb = (((size_t)t * 64 + m32) * 16 + n64g) * 2048;
#pragma unroll
    for (int mf = 0; mf < 2; ++mf)
#pragma unroll
      for (int nf = 0; nf < 4; ++nf) {
        bf16x4 px = *(const bf16x4*)&Pc[tb + (size_t)((mf * 4 + nf) * 64 + lane) * 4];
        int col = n0 + nf * 16 + l16;
        int row = m0 + wm * 32 + mf * 16 + quad * 4;
#pragma unroll
        for (int i = 0; i < 4; ++i) {
          float c = fast_tanh(acc[mf][nf][i] + (float)px[i]);
          size_t idx = (size_t)(row + i) * HID + col;
          float u = u32[idx];
          float hnew = u * h32[idx] + (1.f - u) * c;
          h32[idx] = hnew;
          hb[idx] = (__bf16)hnew;
          out[(size_t)(row + i) * (T_SEQ * HID) + t * HID + col] = hnew;
        }
      }
  }
}

extern "C" void kernel_launch(void* const* d_in, const int* in_sizes, int n_in,
                              void* d_out, int out_size, void* d_ws, size_t ws_size,
                              hipStream_t stream) {
  const float* x     = (const float*)d_in[0];
  const float* coded = (const float*)d_in[1];
  const float* Wg_f  = (const float*)d_in[2];
  const float* bg    = (const float*)d_in[3];
  const float* Wc_f  = (const float*)d_in[4];
  const float* bc    = (const float*)d_in[5];
  float* out = (float*)d_out;

  uintptr_t base = ((uintptr_t)d_ws + 255) & ~(uintptr_t)255;
  auto take = [&](size_t bytes) {
    void* p = (void*)base;
    base = (base + bytes + 255) & ~(uintptr_t)255;
    return p;
  };
  // packed weights (B-frag order)
  __bf16* Bx  = (__bf16*)take((size_t)(NPRE / 16) * 16 * 512 * 2);   // 3.1 MB (K=512)
  __bf16* Bhg = (__bf16*)take((size_t)(NGATE / 16) * 32 * 512 * 2);  // 4.2 MB (K=1024)
  __bf16* Bhc = (__bf16*)take((size_t)(HID / 16) * 32 * 512 * 2);    // 2.1 MB
  // activations / state
  __bf16* Xb  = (__bf16*)take((size_t)BATCH * T_SEQ * IND * 2);      // 25.2 MB
  __bf16* Pg  = (__bf16*)take((size_t)T_SEQ * 64 * 32 * 2048 * 2);   // 100.7 MB
  __bf16* Pc  = (__bf16*)take((size_t)T_SEQ * 64 * 16 * 2048 * 2);   // 50.3 MB
  float*  h32 = (float*) take((size_t)BATCH * HID * 4);
  __bf16* hb  = (__bf16*)take((size_t)BATCH * HID * 2);
  float*  u32 = (float*) take((size_t)BATCH * HID * 4);
  __bf16* rhb = (__bf16*)take((size_t)BATCH * HID * 2);

  // pack weights: x-parts (combined Bx: n16 0..127 gate, 128..191 cand), h-parts
  pack_w<<<(NGATE / 16) * 16 * 64 / 256, 256, 0, stream>>>(Wg_f, NGATE, 0, 16, Bx);
  pack_w<<<(HID / 16) * 16 * 64 / 256, 256, 0, stream>>>(
      Wc_f, HID, 0, 16, Bx + (size_t)(NGATE / 16) * 16 * 512);
  pack_w<<<(NGATE / 16) * 32 * 64 / 256, 256, 0, stream>>>(Wg_f, NGATE, IND, 32, Bhg);
  pack_w<<<(HID / 16) * 32 * 64 / 256, 256, 0, stream>>>(Wc_f, HID, IND, 32, Bhc);
  cvt_bf16<<<(BATCH * T_SEQ * IND / 4 + 255) / 256, 256, 0, stream>>>(
      (const float4*)x, Xb, BATCH * T_SEQ * IND / 4);
  init_h<<<(BATCH * HID / 4 + 255) / 256, 256, 0, stream>>>(
      (const float4*)coded, (float4*)h32, hb, BATCH * HID / 4);

  // x-projection for all timesteps (parallel): M=2048 per t, N=3072, K=512
  gk<2, 8, 0><<<dim3(NPRE / 128, BATCH / 64, T_SEQ), 256, 0, stream>>>(
      Xb, T_SEQ * IND, Bx, bg, bc, Pg, Pc, h32, hb, u32, rhb, out, 0);

  // recurrence: gate (N=2048, K=1024), cand (N=1024, K=1024)
  for (int t = 0; t < T_SEQ; ++t) {
    gk<2, 16, 1><<<dim3(NGATE / 128, BATCH / 64), 256, 0, stream>>>(
        hb, HID, Bhg, bg, bc, Pg, Pc, h32, hb, u32, rhb, out, t);
    gk<1, 16, 2><<<dim3(HID / 64, BATCH / 64), 128, 0, stream>>>(
        rhb, HID, Bhc, bg, bc, Pg, Pc, h32, hb, u32, rhb, out, t);
  }
}